// Round 1
// baseline (173.252 us; speedup 1.0000x reference)
//
#include <hip/hip_runtime.h>
#include <cmath>

// ---------------------------------------------------------------------------
// Problem constants (from reference)
// ---------------------------------------------------------------------------
constexpr int kNsh    = 9;      // (LMAX+1)^2, LMAX=2
constexpr int kF      = 64;
constexpr int kNrbf   = 20;
constexpr int kNAtoms = 1000;
constexpr int kNPairs = 10000;
constexpr float kCutoffF = 5.0f;
constexpr int kMaxNZ  = 200;

// ---------------------------------------------------------------------------
// Compile-time real Clebsch-Gordan table (mirrors the reference _real_cg)
// ---------------------------------------------------------------------------
struct CGSparse {
  int n;
  int c[kMaxNZ];
  int a[kMaxNZ];
  int b[kMaxNZ];
  float v[kMaxNZ];
};

constexpr double cfact(int n) {
  double r = 1.0;
  for (int i = 2; i <= n; i++) r *= (double)i;
  return r;
}
constexpr double cabs_(double x) { return x < 0 ? -x : x; }
constexpr double csqrt_(double x) {
  if (x <= 0.0) return 0.0;
  double g = x < 1.0 ? 1.0 : x;
  for (int i = 0; i < 60; i++) g = 0.5 * (g + x / g);
  return g;
}

constexpr double cg_cplx(int l1, int m1, int l2, int m2, int l3, int m3) {
  if (m3 != m1 + m2) return 0.0;
  int lo = l1 > l2 ? l1 - l2 : l2 - l1;
  if (l3 < lo || l3 > l1 + l2) return 0.0;
  double pre = csqrt_((2 * l3 + 1) * cfact(l3 + l1 - l2) * cfact(l3 - l1 + l2) *
                      cfact(l1 + l2 - l3) / cfact(l1 + l2 + l3 + 1));
  pre *= csqrt_(cfact(l3 + m3) * cfact(l3 - m3) * cfact(l1 - m1) *
                cfact(l1 + m1) * cfact(l2 - m2) * cfact(l2 + m2));
  double s = 0.0;
  for (int k = 0; k <= l1 + l2 - l3; k++) {
    int d0 = k, d1 = l1 + l2 - l3 - k, d2 = l1 - m1 - k;
    int d3 = l2 + m2 - k, d4 = l3 - l2 + m1 + k, d5 = l3 - l1 - m2 + k;
    if (d0 < 0 || d1 < 0 || d2 < 0 || d3 < 0 || d4 < 0 || d5 < 0) continue;
    double den = cfact(d0) * cfact(d1) * cfact(d2) * cfact(d3) * cfact(d4) * cfact(d5);
    s += ((k % 2) ? -1.0 : 1.0) / den;
  }
  return pre * s;
}

constexpr CGSparse build_cg() {
  CGSparse out{};
  int lidx[9] = {0, 1, 1, 1, 2, 2, 2, 2, 2};
  int midx[9] = {0, -1, 0, 1, -2, -1, 0, 1, 2};
  // U matrix (complex -> real SH transform), stored as (re, im)
  double Ur[9][9] = {};
  double Ui[9][9] = {};
  for (int l = 0; l <= 2; l++) {
    int base = l * l + l;
    Ur[base][base] = 1.0;
    for (int m = 1; m <= l; m++) {
      double s2 = 1.0 / csqrt_(2.0);
      double sgn = (m % 2) ? -1.0 : 1.0;
      Ur[base + m][base - m] = s2;
      Ur[base + m][base + m] = sgn * s2;
      Ui[base - m][base - m] = s2;
      Ui[base - m][base + m] = -sgn * s2;
    }
  }
  // cgr stored already transposed: cgr[c][a][b] = einsum result [a][b][c]
  double cgr[9][9][9] = {};
  for (int i = 0; i < 9; i++)
    for (int j = 0; j < 9; j++)
      for (int k = 0; k < 9; k++) {
        double cv = cg_cplx(lidx[i], midx[i], lidx[j], midx[j], lidx[k], midx[k]);
        if (cv == 0.0) continue;
        for (int a2 = 0; a2 < 9; a2++) {
          if (Ur[a2][i] == 0.0 && Ui[a2][i] == 0.0) continue;
          for (int b2 = 0; b2 < 9; b2++) {
            if (Ur[b2][j] == 0.0 && Ui[b2][j] == 0.0) continue;
            for (int c2 = 0; c2 < 9; c2++) {
              if (Ur[c2][k] == 0.0 && Ui[c2][k] == 0.0) continue;
              double ar = Ur[a2][i], ai = Ui[a2][i];
              double br = Ur[b2][j], bi = Ui[b2][j];
              double cr = Ur[c2][k], ci = -Ui[c2][k];  // conj
              double pr = ar * br - ai * bi;
              double pi = ar * bi + ai * br;
              double rr = pr * cr - pi * ci;  // real part
              cgr[c2][a2][b2] += rr * cv;
            }
          }
        }
      }
  // parity mask + sparsify
  int n = 0;
  for (int c2 = 0; c2 < 9; c2++)
    for (int a2 = 0; a2 < 9; a2++)
      for (int b2 = 0; b2 < 9; b2++) {
        bool mask = ((lidx[a2] + lidx[b2]) % 2) == (lidx[c2] % 2);
        double v = mask ? cgr[c2][a2][b2] : 0.0;
        if (cabs_(v) > 1e-9) {
          out.c[n] = c2;
          out.a[n] = a2;
          out.b[n] = b2;
          out.v[n] = (float)v;
          n++;
        }
      }
  out.n = n;
  return out;
}

constexpr CGSparse CG = build_cg();
static_assert(CG.n > 0 && CG.n <= kMaxNZ, "CG table size out of range");

// ---------------------------------------------------------------------------
// Kernels
// ---------------------------------------------------------------------------

// x[atom, c, f]: zero everywhere, x[:,0,:] = emb[Z]
__global__ void k_init_x(const int* __restrict__ Z, const float* __restrict__ emb,
                         float* __restrict__ x) {
  int tid = blockIdx.x * blockDim.x + threadIdx.x;
  if (tid >= kNAtoms * kNsh * kF) return;
  int f = tid & 63;
  int c = (tid >> 6) % kNsh;
  int atom = tid / (kNsh * kF);
  float v = 0.0f;
  if (c == 0) v = emb[Z[atom] * kF + f];
  x[tid] = v;
}

// Per-pair geometry: Y[9], cut, radial[20] -> pairdata[p*32 + ...]
__global__ void k_pair_pre(const float* __restrict__ rij, float* __restrict__ pd_all) {
  int p = blockIdx.x * blockDim.x + threadIdx.x;
  if (p >= kNPairs) return;
  float rx = rij[3 * p + 0], ry = rij[3 * p + 1], rz = rij[3 * p + 2];
  float d = sqrtf(rx * rx + ry * ry + rz * rz);
  float inv = 1.0f / d;
  float x = rx * inv, y = ry * inv, z = rz * inv;
  const float c0 = 0.28209479177387814f;  // 0.5/sqrt(pi)
  const float c1 = 0.4886025119029199f;   // sqrt(3/(4pi))
  const float c2 = 1.0925484305920792f;   // 0.5*sqrt(15/pi)
  const float c3 = 0.31539156525252005f;  // 0.25*sqrt(5/pi)
  const float c4 = 0.5462742152960396f;   // 0.25*sqrt(15/pi)
  float* pd = pd_all + p * 32;
  pd[0] = c0;
  pd[1] = c1 * y;
  pd[2] = c1 * z;
  pd[3] = c1 * x;
  pd[4] = c2 * x * y;
  pd[5] = c2 * y * z;
  pd[6] = c3 * (3.0f * z * z - 1.0f);
  pd[7] = c2 * x * z;
  pd[8] = c4 * (x * x - y * y);
  float cut = (d < kCutoffF) ? 0.5f * (cosf(d * (float)(M_PI / 5.0)) + 1.0f) : 0.0f;
  pd[9] = cut;
  const float width = kCutoffF / (kNrbf - 1);
  const float coef = -0.5f / (width * width);
  for (int k = 0; k < kNrbf; k++) {
    float off = (kCutoffF * k) / (kNrbf - 1);
    float t = d - off;
    pd[10 + k] = expf(coef * t * t);
  }
}

// One wave (64 lanes, lane = feature f) per pair. Message + atomic scatter.
__global__ __launch_bounds__(256) void k_message(
    const float* __restrict__ x, const int* __restrict__ idx_i,
    const int* __restrict__ idx_j, const float* __restrict__ pd_all,
    const float* __restrict__ Wf, const float* __restrict__ bf,
    float* __restrict__ dxbuf) {
  int wave = threadIdx.x >> 6;
  int f = threadIdx.x & 63;
  int p = blockIdx.x * (blockDim.x >> 6) + wave;
  if (p >= kNPairs) return;
  const float* pd = pd_all + p * 32;
  float cut = pd[9];
  // W[l][f] = (radial @ Wf + bf) * cut
  float W0 = bf[0 * kF + f], W1v = bf[1 * kF + f], W2v = bf[2 * kF + f];
  #pragma unroll
  for (int k = 0; k < kNrbf; k++) {
    float r = pd[10 + k];
    W0 += r * Wf[k * 192 + 0 * kF + f];
    W1v += r * Wf[k * 192 + 1 * kF + f];
    W2v += r * Wf[k * 192 + 2 * kF + f];
  }
  W0 *= cut; W1v *= cut; W2v *= cut;
  // YW[b] = Y[b] * W[l_b]
  float YW[9];
  YW[0] = pd[0] * W0;
  YW[1] = pd[1] * W1v;
  YW[2] = pd[2] * W1v;
  YW[3] = pd[3] * W1v;
  #pragma unroll
  for (int b = 4; b < 9; b++) YW[b] = pd[b] * W2v;
  // gather x[j]
  int j = idx_j[p];
  float xv[9];
  #pragma unroll
  for (int a = 0; a < 9; a++) xv[a] = x[j * (kNsh * kF) + a * kF + f];
  // sparse CG contraction (fully unrolled, constant indices)
  float y[9] = {0, 0, 0, 0, 0, 0, 0, 0, 0};
  #pragma unroll
  for (int e = 0; e < CG.n; e++) {
    y[CG.c[e]] += CG.v[e] * YW[CG.b[e]] * xv[CG.a[e]];
  }
  int i = idx_i[p];
  #pragma unroll
  for (int c = 0; c < 9; c++) {
    atomicAdd(&dxbuf[i * (kNsh * kF) + c * kF + f], y[c]);
  }
}

// One 64-thread block per atom: ddx = dx@W1; tp = CG(dx, ddx);
// dx2 = (dx+tp)@W2; gate = sigmoid(dx2[0]@Wg + bg); dx3 = dx2*gate[lidx];
// x += dx3@W3
__global__ __launch_bounds__(64) void k_update(
    const float* __restrict__ dxbuf, const float* __restrict__ W1,
    const float* __restrict__ W2, const float* __restrict__ W3,
    const float* __restrict__ Wg, const float* __restrict__ bg,
    float* __restrict__ x) {
  int atom = blockIdx.x;
  int f = threadIdx.x;
  __shared__ float s[kNsh][kF];

  float dxv[9];
  #pragma unroll
  for (int c = 0; c < 9; c++) {
    dxv[c] = dxbuf[atom * (kNsh * kF) + c * kF + f];
    s[c][f] = dxv[c];
  }
  __syncthreads();
  // ddx = dx @ W1
  float ddx[9] = {0, 0, 0, 0, 0, 0, 0, 0, 0};
  for (int k = 0; k < kF; k++) {
    float w = W1[k * kF + f];
    #pragma unroll
    for (int c = 0; c < 9; c++) ddx[c] += s[c][k] * w;
  }
  // tp (sparse CG, per-feature elementwise) ; t2 = dx + tp
  float t2[9];
  #pragma unroll
  for (int c = 0; c < 9; c++) t2[c] = dxv[c];
  #pragma unroll
  for (int e = 0; e < CG.n; e++) {
    t2[CG.c[e]] += CG.v[e] * dxv[CG.a[e]] * ddx[CG.b[e]];
  }
  __syncthreads();
  #pragma unroll
  for (int c = 0; c < 9; c++) s[c][f] = t2[c];
  __syncthreads();
  // dx2 = (dx+tp) @ W2
  float dx2[9] = {0, 0, 0, 0, 0, 0, 0, 0, 0};
  for (int k = 0; k < kF; k++) {
    float w = W2[k * kF + f];
    #pragma unroll
    for (int c = 0; c < 9; c++) dx2[c] += s[c][k] * w;
  }
  __syncthreads();
  #pragma unroll
  for (int c = 0; c < 9; c++) s[c][f] = dx2[c];
  __syncthreads();
  // gate from dx2[:,0]
  float g0 = bg[0 * kF + f], g1 = bg[1 * kF + f], g2 = bg[2 * kF + f];
  for (int k = 0; k < kF; k++) {
    float v0 = s[0][k];
    g0 += v0 * Wg[k * 192 + 0 * kF + f];
    g1 += v0 * Wg[k * 192 + 1 * kF + f];
    g2 += v0 * Wg[k * 192 + 2 * kF + f];
  }
  g0 = 1.0f / (1.0f + expf(-g0));
  g1 = 1.0f / (1.0f + expf(-g1));
  g2 = 1.0f / (1.0f + expf(-g2));
  const float gl[3] = {g0, g1, g2};
  const int lidx_[9] = {0, 1, 1, 1, 2, 2, 2, 2, 2};
  float dx3[9];
  #pragma unroll
  for (int c = 0; c < 9; c++) dx3[c] = dx2[c] * gl[lidx_[c]];
  __syncthreads();
  #pragma unroll
  for (int c = 0; c < 9; c++) s[c][f] = dx3[c];
  __syncthreads();
  // out = dx3 @ W3 ; x += out
  float outv[9] = {0, 0, 0, 0, 0, 0, 0, 0, 0};
  for (int k = 0; k < kF; k++) {
    float w = W3[k * kF + f];
    #pragma unroll
    for (int c = 0; c < 9; c++) outv[c] += s[c][k] * w;
  }
  #pragma unroll
  for (int c = 0; c < 9; c++) {
    x[atom * (kNsh * kF) + c * kF + f] += outv[c];
  }
}

// ---------------------------------------------------------------------------
// Launch
// ---------------------------------------------------------------------------
extern "C" void kernel_launch(void* const* d_in, const int* in_sizes, int n_in,
                              void* d_out, int out_size, void* d_ws, size_t ws_size,
                              hipStream_t stream) {
  const int* Z        = (const int*)d_in[0];
  const float* rij    = (const float*)d_in[1];
  const int* idx_i    = (const int*)d_in[2];
  const int* idx_j    = (const int*)d_in[3];
  const float* emb    = (const float*)d_in[4];
  const float* Wf     = (const float*)d_in[5];
  const float* bf     = (const float*)d_in[6];
  const float* W1     = (const float*)d_in[7];
  const float* W2     = (const float*)d_in[8];
  const float* W3     = (const float*)d_in[9];
  const float* Wg     = (const float*)d_in[10];
  const float* bg     = (const float*)d_in[11];
  float* x = (float*)d_out;

  float* dxbuf = (float*)d_ws;                       // 576000 floats
  float* pairdata = dxbuf + kNAtoms * kNsh * kF;     // 10000*32 floats

  k_init_x<<<(kNAtoms * kNsh * kF + 255) / 256, 256, 0, stream>>>(Z, emb, x);
  k_pair_pre<<<(kNPairs + 255) / 256, 256, 0, stream>>>(rij, pairdata);

  for (int t = 0; t < 2; t++) {
    hipMemsetAsync(dxbuf, 0, (size_t)kNAtoms * kNsh * kF * sizeof(float), stream);
    k_message<<<(kNPairs + 3) / 4, 256, 0, stream>>>(
        x, idx_i, idx_j, pairdata, Wf + t * kNrbf * 192, bf + t * 192, dxbuf);
    k_update<<<kNAtoms, 64, 0, stream>>>(
        dxbuf, W1 + t * kF * kF, W2 + t * kF * kF, W3 + t * kF * kF,
        Wg + t * kF * 192, bg + t * 192, x);
  }
}